// Round 7
// baseline (252.609 us; speedup 1.0000x reference)
//
#include <hip/hip_runtime.h>

typedef unsigned short u16;
typedef unsigned int u32;

#define B_    2
#define T_    2048
#define C_    2048
#define NH_   16
#define NKVH_ 4
#define HS_   128
#define KV_   512
#define NQKV  3072
#define M_    4096   // B*T
#define SCALE 0.08838834764831845f
#define CC    0.12751742f     // SCALE * log2(e)
#define THR_RAW 62.0f         // defer-max threshold (raw-score units, ~8/CC)

typedef __bf16 bf16x8 __attribute__((ext_vector_type(8)));
typedef float  f32x4  __attribute__((ext_vector_type(4)));
typedef float  f32x16 __attribute__((ext_vector_type(16)));
typedef unsigned int u32x2 __attribute__((ext_vector_type(2)));

__device__ __forceinline__ float bf2f(u16 u) {
    union { u32 i; float f; } x; x.i = ((u32)u) << 16; return x.f;
}
__device__ __forceinline__ u16 f2bf(float f) {
    union { float f; u32 i; } x; x.f = f;
    u32 r = x.i + 0x7fffu + ((x.i >> 16) & 1u);
    return (u16)(r >> 16);
}
__device__ __forceinline__ u32 cvtpk(float lo, float hi) {
    u32 r; asm("v_cvt_pk_bf16_f32 %0, %1, %2" : "=v"(r) : "v"(lo), "v"(hi));
    return r;
}

// async global->LDS, 16B per lane; LDS dest = wave-uniform base + lane*16
__device__ __forceinline__ void gload16(const void* g, void* l) {
    __builtin_amdgcn_global_load_lds(
        (const __attribute__((address_space(1))) u32*)g,
        (__attribute__((address_space(3))) u32*)l,
        16, 0, 0);
}

// ---------------- cast x (f32 -> bf16) ----------------
__global__ __launch_bounds__(256) void cast_f32_bf16(
    const float* __restrict__ in, u16* __restrict__ out, int n)
{
    int idx = (blockIdx.x * 256 + threadIdx.x) * 4;
    if (idx < n) {
        float4 v = *reinterpret_cast<const float4*>(in + idx);
        u32 p0 = (u32)f2bf(v.x) | ((u32)f2bf(v.y) << 16);
        u32 p1 = (u32)f2bf(v.z) | ((u32)f2bf(v.w) << 16);
        u32* o = (u32*)(out + idx);
        o[0] = p0; o[1] = p1;
    }
}

// ---------------- transpose + cast (f32 RxC -> bf16 CxR) ----------------
__global__ __launch_bounds__(256) void transpose_cast_f32_bf16(
    const float* __restrict__ in, u16* __restrict__ out, int R, int Cc)
{
    __shared__ float tile[32][33];
    int c0 = blockIdx.x * 32, r0 = blockIdx.y * 32;
    int tx = threadIdx.x & 31, ty = threadIdx.x >> 5;  // 32 x 8
#pragma unroll
    for (int i = 0; i < 4; ++i)
        tile[ty + i * 8][tx] = in[(size_t)(r0 + ty + i * 8) * Cc + c0 + tx];
    __syncthreads();
#pragma unroll
    for (int i = 0; i < 4; ++i)
        out[(size_t)(c0 + ty + i * 8) * R + r0 + tx] = f2bf(tile[tx][ty + i * 8]);
}

// ---------------- batched bf16 transpose (z, R, Cc) -> (z, Cc, R) ----------------
__global__ __launch_bounds__(256) void transpose_bf16_batched(
    const u16* __restrict__ in, u16* __restrict__ out, int R, int Cc)
{
    __shared__ u16 tile[32][33];
    int c0 = blockIdx.x * 32, r0 = blockIdx.y * 32;
    size_t zb = (size_t)blockIdx.z * R * Cc;
    int tx = threadIdx.x & 31, ty = threadIdx.x >> 5;
#pragma unroll
    for (int i = 0; i < 4; ++i)
        tile[ty + i * 8][tx] = in[zb + (size_t)(r0 + ty + i * 8) * Cc + c0 + tx];
    __syncthreads();
#pragma unroll
    for (int i = 0; i < 4; ++i)
        out[zb + (size_t)(c0 + ty + i * 8) * R + r0 + tx] = tile[tx][ty + i * 8];
}

// ======== 8-phase MFMA GEMM: C[M,N] = A[M,K]*Bt[N,K]^T + bias ========
// EPI: 0 = plain f32 C-write; 2 = fused RoPE + q/k/v scatter (gemm1).
// Tile (MFRAG*32) x 256, 512 thr = 8 waves (2M x 4N). BK=64, K-split halves;
// register reads pipelined one phase ahead; vmcnt(2*LA+LB) ledger per tile.
template <int MFRAG, int EPI>
__global__ __launch_bounds__(512, 2) void gemm8(
    const u16* __restrict__ A, const u16* __restrict__ Bt,
    const float* __restrict__ bias, void* __restrict__ Cv,
    int M, int N, int K,
    const float* __restrict__ fcos, const float* __restrict__ fsin,
    u16* __restrict__ qb, u16* __restrict__ kb, u16* __restrict__ vb,
    float* __restrict__ kc, float* __restrict__ vc)
{
    constexpr int MH = MFRAG / 2;       // m-frags per m-half
    constexpr int LA = MFRAG / 4;       // gload16 per A half-tile per wave
    constexpr int ASZ = MFRAG * 1024;   // elements per A half
    __shared__ __attribute__((aligned(16))) u16 As[2][2][ASZ];
    __shared__ __attribute__((aligned(16))) u16 Bs[2][2][8192];

    int tid = threadIdx.x, lane = tid & 63, w = tid >> 6;
    int l16 = lane & 15, hi = (lane >> 4) & 3;
    int wm = w >> 2, wn = w & 3;

    // bijective XCD swizzle (nwg % 8 == 0 for all our grids)
    int gx = gridDim.x, nwg = gx * gridDim.y;
    int id = blockIdx.y * gx + blockIdx.x;
    int nid = (id & 7) * (nwg >> 3) + (id >> 3);
    int brow = (nid % gx) * (MFRAG * 32), bcol = (nid / gx) * 256;

    const int NT = K >> 6;
    f32x4 acc[MFRAG][4] = {};

    auto stageA = [&](int kt2, int kk, int buf) {
#pragma unroll
        for (int i = 0; i < LA; ++i) {
            u32 off = (u32)i * 8192 + (u32)w * 1024 + ((u32)lane << 4);
            u32 g = off ^ (((off >> 7) & 7) << 4);
            u32 r = g >> 6, s = (g >> 4) & 3;
            gload16(A + (size_t)(brow + r) * K + kt2 * 64 + kk * 32 + s * 8,
                    (char*)&As[buf][kk][0] + i * 8192 + w * 1024);
        }
    };
    auto stageB = [&](int kt2, int kk, int buf) {
#pragma unroll
        for (int i = 0; i < 2; ++i) {
            u32 off = (u32)i * 8192 + (u32)w * 1024 + ((u32)lane << 4);
            u32 g = off ^ (((off >> 7) & 7) << 4);
            u32 r = g >> 6, s = (g >> 4) & 3;
            gload16(Bt + (size_t)(bcol + r) * K + kt2 * 64 + kk * 32 + s * 8,
                    (char*)&Bs[buf][kk][0] + i * 8192 + w * 1024);
        }
    };
    auto readA = [&](const u16* base, int mh, bf16x8* dst) {
#pragma unroll
        for (int m = 0; m < MH; ++m) {
            u32 a = (u32)((wm * MFRAG + mh * MH + m) * 16 + l16) * 64 + (u32)hi * 16;
            dst[m] = *reinterpret_cast<const bf16x8*>(
                (const char*)base + (a ^ (((a >> 7) & 7) << 4)));
        }
    };
    auto readB = [&](const u16* base, bf16x8* dst) {
#pragma unroll
        for (int n = 0; n < 4; ++n) {
            u32 a = (u32)(wn * 64 + n * 16 + l16) * 64 + (u32)hi * 16;
            dst[n] = *reinterpret_cast<const bf16x8*>(
                (const char*)base + (a ^ (((a >> 7) & 7) << 4)));
        }
    };

    // prologue: tile0 all 4 halves + tile1 {A0, B0, A1}; drain tile0
    stageA(0, 0, 0); stageB(0, 0, 0); stageA(0, 1, 0); stageB(0, 1, 0);
    if (NT > 1) {
        stageA(1, 0, 1); stageB(1, 0, 1); stageA(1, 1, 1);
        if constexpr (MFRAG == 8) asm volatile("s_waitcnt vmcnt(6)" ::: "memory");
        else                      asm volatile("s_waitcnt vmcnt(4)" ::: "memory");
    } else {
        asm volatile("s_waitcnt vmcnt(0)" ::: "memory");
    }
    __builtin_amdgcn_s_barrier();

    for (int kt = 0; kt < NT; ++kt) {
        int cur = kt & 1, nxt = cur ^ 1;
        const u16* Ac0 = &As[cur][0][0];
        const u16* Ac1 = &As[cur][1][0];
        const u16* Bc0 = &Bs[cur][0][0];
        const u16* Bc1 = &Bs[cur][1][0];
        bf16x8 af0[MH], af1[MH], af2[MH], af3[MH], bf0[4], bf1[4];

        // ---- P0: read q0+q1 operands; stage B1(kt+1) ----
        readA(Ac0, 0, af0); readB(Bc0, bf0); readA(Ac0, 1, af1);
        if (kt + 1 < NT) stageB(kt + 1, 1, nxt);
        __builtin_amdgcn_s_barrier();
        __builtin_amdgcn_s_setprio(1);
#pragma unroll
        for (int m = 0; m < MH; ++m)
#pragma unroll
            for (int n = 0; n < 4; ++n)
                acc[m][n] = __builtin_amdgcn_mfma_f32_16x16x32_bf16(
                    af0[m], bf0[n], acc[m][n], 0, 0, 0);
        __builtin_amdgcn_s_setprio(0);
        __builtin_amdgcn_s_barrier();

        // ---- P1: read q2 operands; stage A0(kt+2) ----
        readA(Ac1, 0, af2); readB(Bc1, bf1);
        if (kt + 2 < NT) stageA(kt + 2, 0, cur);
        __builtin_amdgcn_s_barrier();
        __builtin_amdgcn_s_setprio(1);
#pragma unroll
        for (int m = 0; m < MH; ++m)
#pragma unroll
            for (int n = 0; n < 4; ++n)
                acc[MH + m][n] = __builtin_amdgcn_mfma_f32_16x16x32_bf16(
                    af1[m], bf0[n], acc[MH + m][n], 0, 0, 0);
        __builtin_amdgcn_s_setprio(0);
        __builtin_amdgcn_s_barrier();

        // ---- P2: read q3 operands; stage B0(kt+2) ----
        readA(Ac1, 1, af3);
        if (kt + 2 < NT) stageB(kt + 2, 0, cur);
        __builtin_amdgcn_s_barrier();
        __builtin_amdgcn_s_setprio(1);
#pragma unroll
        for (int m = 0; m < MH; ++m)
#pragma unroll
            for (int n = 0; n < 4; ++n)
                acc[m][n] = __builtin_amdgcn_mfma_f32_16x16x32_bf16(
                    af2[m], bf1[n], acc[m][n], 0, 0, 0);
        __builtin_amdgcn_s_setprio(0);
        __builtin_amdgcn_s_barrier();

        // ---- P3: stage A1(kt+2); end-of-tile counted wait ----
        if (kt + 2 < NT) stageA(kt + 2, 1, cur);
        __builtin_amdgcn_s_barrier();
        __builtin_amdgcn_s_setprio(1);
#pragma unroll
        for (int m = 0; m < MH; ++m)
#pragma unroll
            for (int n = 0; n < 4; ++n)
                acc[MH + m][n] = __builtin_amdgcn_mfma_f32_16x16x32_bf16(
                    af3[m], bf1[n], acc[MH + m][n], 0, 0, 0);
        __builtin_amdgcn_s_setprio(0);
        if (kt + 1 < NT) {
            if (kt + 2 < NT) {
                if constexpr (MFRAG == 8) asm volatile("s_waitcnt vmcnt(6)" ::: "memory");
                else                      asm volatile("s_waitcnt vmcnt(4)" ::: "memory");
            } else {
                asm volatile("s_waitcnt vmcnt(0)" ::: "memory");
            }
        }
        __builtin_amdgcn_s_barrier();
    }

    // ---- epilogue ----
    if constexpr (EPI == 2) {
        // fused RoPE + scatter: each 256-col block is entirely Q, K, or V.
        int sgn = l16 & 1;
#pragma unroll
        for (int n = 0; n < 4; ++n) {
            int col = bcol + wn * 64 + n * 16 + l16;
            float bv = bias[col];
#pragma unroll
            for (int m = 0; m < MFRAG; ++m) {
#pragma unroll
                for (int j = 0; j < 4; ++j) {
                    int row = brow + wm * (MFRAG * 16) + m * 16 + hi * 4 + j;
                    int bb = row >> 11, t = row & 2047;
                    float v = acc[m][n][j] + bv;
                    float pr = __shfl_xor(v, 1);
                    if (col < C_) {                    // Q + RoPE
                        int h = col >> 7, d = col & 127;
                        float c = fcos[t * 64 + (d >> 1)];
                        float s = fsin[t * 64 + (d >> 1)];
                        float out = sgn ? (pr * s + v * c) : (v * c - pr * s);
                        qb[((size_t)(bb * NH_ + h) * T_ + t) * HS_ + d] = f2bf(out);
                    } else if (col < C_ + KV_) {       // K + RoPE (+ f32 cache)
                        int cc = col - C_;
                        int h = cc >> 7, d = cc & 127;
                        float c = fcos[t * 64 + (d >> 1)];
                        float s = fsin[t * 64 + (d >> 1)];
                        float out = sgn ? (pr * s + v * c) : (v * c - pr * s);
                        size_t o = ((size_t)(bb * NKVH_ + h) * T_ + t) * HS_ + d;
                        kb[o] = f2bf(out); kc[o] = out;
                    } else {                           // V (+ f32 cache)
                        int cc = col - C_ - KV_;
                        int h = cc >> 7, d = cc & 127;
                        size_t o = ((size_t)(bb * NKVH_ + h) * T_ + t) * HS_ + d;
                        vb[o] = f2bf(v); vc[o] = v;
                    }
                }
            }
        }
    } else {
#pragma unroll
        for (int n = 0; n < 4; ++n) {
            int col = bcol + wn * 64 + n * 16 + l16;
            float bv = bias[col];
#pragma unroll
            for (int m = 0; m < MFRAG; ++m) {
#pragma unroll
                for (int j = 0; j < 4; ++j) {
                    int row = brow + wm * (MFRAG * 16) + m * 16 + hi * 4 + j;
                    ((float*)Cv)[(size_t)row * N + col] = acc[m][n][j] + bv;
                }
            }
        }
    }
}

// ---------------- flash attention (causal, GQA), 32x32 swapped-QK ----------------
// QBLK=128/block (4 waves x 32 q-rows), KVBLK=64, K/V dbuf + XOR-swizzled.
// (R4-verified form: 85.0 us. No setprio — measured -5% on this structure.)
#define STAGE_KV(it_, buf_)                                               \
  {                                                                       \
    int _it = (it_);                                                      \
    _Pragma("unroll")                                                     \
    for (int i = 0; i < 4; ++i) {                                         \
      int chunk = w * 4 + i;                                              \
      int rk = chunk * 4 + (lane >> 4);                                   \
      int ck = ((lane & 15) ^ (rk & 7)) << 3;                             \
      gload16(Kp + (size_t)(_it * 64 + rk) * HS_ + ck,                    \
              (char*)Ks[buf_] + chunk * 1024);                            \
      int rv = chunk * 8 + (lane >> 3);                                   \
      int cv = ((lane & 7) ^ (rv & 7)) << 3;                              \
      gload16(Vp + (size_t)rv * T_ + _it * 64 + cv,                       \
              (char*)Vs[buf_] + chunk * 1024);                            \
    }                                                                     \
  }

__global__ __launch_bounds__(256, 2) void attn_kernel(
    const u16* __restrict__ qb,   // (B, NH, T, HS)
    const u16* __restrict__ kb,   // (B, NKVH, T, HS)
    const u16* __restrict__ vt,   // (B, NKVH, HS, T)
    u16* __restrict__ aout)       // (B, T, C) bf16
{
    __shared__ __attribute__((aligned(16))) u16 Ks[2][64 * 128];
    __shared__ __attribute__((aligned(16))) u16 Vs[2][128 * 64];

    // load-balance remap: co-resident pair (n, n+256) gets qt summing to 15
    int xx = blockIdx.x, yy = blockIdx.y;
    int qt = (yy < 16) ? (15 - xx) : xx;
    int bh = yy, b = bh >> 4, h = bh & 15, kvh = h >> 2;
    int lane = threadIdx.x & 63, w = threadIdx.x >> 6;
    int l32 = lane & 31, l5 = lane >> 5;
    int xorm = (l32 & 7) << 3;               // element-space XOR for LDS reads
    int koff = 8 * l5;

    const u16* Qp = qb + ((size_t)(b * NH_ + h) * T_ + qt * 128 + w * 32) * HS_;
    const u16* Kp = kb + (size_t)(b * NKVH_ + kvh) * T_ * HS_;
    const u16* Vp = vt + (size_t)(b * NKVH_ + kvh) * HS_ * T_;

    // Q as B-operand frags: row = l32 (q), k = kd*16 + 8*l5 + [0..7]
    bf16x8 qf[8];
#pragma unroll
    for (int kd = 0; kd < 8; ++kd)
        qf[kd] = *reinterpret_cast<const bf16x8*>(
            Qp + (size_t)l32 * HS_ + kd * 16 + koff);

    f32x16 o[4] = {};
    float m = -1e30f, lrow = 0.f;
    int qg = qt * 128 + w * 32 + l32;        // this lane's q row
    int qmaxw = qt * 128 + w * 32 + 31;

    int ntiles = 2 * qt + 2;
    STAGE_KV(0, 0);

    for (int it = 0; it < ntiles; ++it) {
        int buf = it & 1;
        __syncthreads();                     // tile `it` resident
        if (it + 1 < ntiles) STAGE_KV(it + 1, buf ^ 1);

        if (it * 64 <= qmaxw) {              // wave has unmasked work here
            const u16* Kbase = Ks[buf];
            const u16* Vbase = Vs[buf];

            // ---- S = K Q^T : D[kv][q], q = l32 lane-local ----
            f32x16 sacc[2] = {};
#pragma unroll
            for (int kt2 = 0; kt2 < 2; ++kt2)
#pragma unroll
                for (int kd = 0; kd < 8; ++kd) {
                    bf16x8 kf = *reinterpret_cast<const bf16x8*>(
                        Kbase + (kt2 * 32 + l32) * 128 + ((kd * 16 + koff) ^ xorm));
                    sacc[kt2] = __builtin_amdgcn_mfma_f32_32x32x16_bf16(
                        kf, qf[kd], sacc[kt2], 0, 0, 0);
                }

            // ---- causal mask (raw scores; exp folds the scale) ----
            if (it * 64 + 63 > qt * 128 + w * 32) {
#pragma unroll
                for (int kt2 = 0; kt2 < 2; ++kt2)
#pragma unroll
                    for (int r = 0; r < 16; ++r) {
                        int kvg = it * 64 + kt2 * 32 + (r & 3) + 8 * (r >> 2) + 4 * l5;
                        if (kvg > qg) sacc[kt2][r] = -1e30f;
                    }
            }

            // ---- row max (tree + 1 cross-half shuffle) ----
            float mx;
            {
                float t8[8];
#pragma unroll
                for (int i = 0; i < 8; ++i) {
                    float a = fmaxf(sacc[0][i], sacc[0][i + 8]);
                    float c = fmaxf(sacc[1][i], sacc[1][i + 8]);
                    t8[i] = fmaxf(a, c);
                }
                float t4a = fmaxf(t8[0], t8[1]), t4b = fmaxf(t8[2], t8[3]);
                float t4c = fmaxf(t8[4], t8[5]), t4d = fmaxf(t8[6], t8[7]);
                mx = fmaxf(fmaxf(t4a, t4b), fmaxf(t4c, t4d));
                mx = fmaxf(mx, __shfl_xor(mx, 32));
            }

            // ---- defer-max: rescale only when max grew past threshold ----
            if (!__all(mx <= m + THR_RAW)) {
                float nm = fmaxf(m, mx);
                float al = exp2f(CC * (m - nm));
                m = nm;
                lrow *= al;
#pragma unroll
                for (int r = 0; r < 16; ++r) {
                    float af = __shfl(al, (r & 3) + 8 * (r >> 2) + 4 * l5, 64);
                    o[0][r] *= af; o[1][r] *= af; o[2][r] *= af; o[3][r] *= af;
                }
            }
            float mcm = -CC * m;

            // ---- P = 2^(CC*s - CC*m), row sum ----
            f32x16 p[2];
#pragma unroll
            for (int kt2 = 0; kt2 < 2; ++kt2)
#pragma unroll
                for (int r = 0; r < 16; ++r)
                    p[kt2][r] = exp2f(__builtin_fmaf(CC, sacc[kt2][r], mcm));
            {
                float s8[8];
#pragma unroll
                for (int i = 0; i < 8; ++i)
                    s8[i] = (p[0][i] + p[0][i + 8]) + (p[1][i] + p[1][i + 8]);
                float s4a = s8[0] + s8[1], s4b = s8[2] + s8[3];
                float s4c = s8[4] + s8[5], s4d = s8[6] + s8[7];
                float rs = (s4a + s4b) + (s4c + s4d);
                rs += __shfl_xor(rs, 32);
                lrow += rs;
            }

            // ---- PV: build A-frags in-register (cvt_pk + permlane32_swap) ----
#pragma unroll
            for (int ks = 0; ks < 4; ++ks) {
                int e = ks & 1, kh = ks >> 1;
                u32 a0 = cvtpk(p[kh][8 * e + 0], p[kh][8 * e + 1]);
                u32 a1 = cvtpk(p[kh][8 * e + 2], p[kh][8 * e + 3]);
                u32 b0 = cvtpk(p[kh][8 * e + 4], p[kh][8 * e + 5]);
                u32 b1 = cvtpk(p[kh][8 * e + 6], p[kh][8 * e + 7]);
                u32x2 s0 = __builtin_amdgcn_permlane32_swap(a0, b0, false, false);
                u32x2 s1 = __builtin_amdgcn_permlane32_swap(a1, b1, false, false);
                union { u32 u[4]; bf16x8 v; } pu;
                pu.u[0] = s0[0]; pu.u[1] = s1[0]; pu.u[2] = s0[1]; pu.u[3] = s1[1];
                bf16x8 pf = pu.v;
#pragma unroll
                for (int dt = 0; dt < 4; ++dt) {
                    bf16x8 vf = *reinterpret_cast<const bf16x8*>(
                        Vbase + (dt * 32 + l32) * 64 + ((ks * 16 + koff) ^ xorm));
                    o[dt] = __builtin_amdgcn_mfma_f32_32x32x16_bf16(
                        pf, vf, o[dt], 0, 0, 0);
                }
            }
        }
    }

    // ---- epilogue: normalize (broadcast 1/l to reg-dim) and store ----
    float inv = 1.0f / lrow;
#pragma unroll
    for (int r = 0; r < 16; ++r) {
        int ql = (r & 3) + 8 * (r >> 2) + 4 * l5;
        float iv = __shfl(inv, ql, 64);
        int trow = qt * 128 + w * 32 + ql;
        size_t base = ((size_t)b * T_ + trow) * C_ + h * HS_ + l32;
#pragma unroll
        for (int dt = 0; dt < 4; ++dt)
            aout[base + dt * 32] = f2bf(o[dt][r] * iv);
    }
}

// ---------------- launch ----------------
extern "C" void kernel_launch(void* const* d_in, const int* in_sizes, int n_in,
                              void* d_out, int out_size, void* d_ws, size_t ws_size,
                              hipStream_t stream)
{
    const float* x      = (const float*)d_in[0];
    const float* w_qkv  = (const float*)d_in[1];
    const float* b_qkv  = (const float*)d_in[2];
    const float* w_proj = (const float*)d_in[3];
    const float* b_proj = (const float*)d_in[4];
    const float* fcos   = (const float*)d_in[5];
    const float* fsin   = (const float*)d_in[6];

    float* y  = (float*)d_out;
    float* kc = y + (size_t)B_ * T_ * C_;
    float* vc = kc + (size_t)B_ * NKVH_ * T_ * HS_;

    // workspace layout (58.7 MB total; no live overlaps):
    //  [0, 16.8M): xb (live through gemm1) -> then wprojT @0 (8.4M), vtb @8.4M (4.2M)
    //  [16.8M, 29.4M): wqkvT (live through gemm1) -> then aout @16.8M (16.8M)
    //  [33.6M, 50.3M): qbuf   [50.3M, 54.5M): kbuf   [54.5M, 58.7M): vbuf
    char* ws = (char*)d_ws;
    u16* xb     = (u16*)(ws);
    u16* wprojT = (u16*)(ws);
    u16* vtb    = (u16*)(ws + 8388608);
    u16* wqkvT  = (u16*)(ws + 16777216);
    u16* aout   = (u16*)(ws + 16777216);
    u16* qbuf   = (u16*)(ws + 33554432);
    u16* kbuf   = (u16*)(ws + 50331648);
    u16* vbuf   = (u16*)(ws + 54525952);

    // 1. cast x -> bf16
    cast_f32_bf16<<<M_ * C_ / 1024, 256, 0, stream>>>(x, xb, M_ * C_);
    // 2. w_qkv (C, NQKV) -> wqkvT (NQKV, C) bf16
    transpose_cast_f32_bf16<<<dim3(NQKV / 32, C_ / 32), 256, 0, stream>>>(
        w_qkv, wqkvT, C_, NQKV);
    // 3. gemm1 with fused RoPE+scatter: writes qbuf/kbuf/vbuf + fp32 kc/vc
    gemm8<8, 2><<<dim3(M_ / 256, NQKV / 256), 512, 0, stream>>>(
        xb, wqkvT, b_qkv, nullptr, M_, NQKV, C_,
        fcos, fsin, qbuf, kbuf, vbuf, kc, vc);
    // 4. V (b,kvh,T,HS) -> V^T (b,kvh,HS,T)
    transpose_bf16_batched<<<dim3(HS_ / 32, T_ / 32, B_ * NKVH_), 256, 0, stream>>>(
        vbuf, vtb, T_, HS_);
    // 5. w_proj (C,C) -> wprojT bf16 (into dead xb region)
    transpose_cast_f32_bf16<<<dim3(C_ / 32, C_ / 32), 256, 0, stream>>>(
        w_proj, wprojT, C_, C_);
    // 6. attention (writes aout into dead wqkvT region)
    attn_kernel<<<dim3(T_ / 128, B_ * NH_), 256, 0, stream>>>(qbuf, kbuf, vtb, aout);
    // 7. y = aout @ w_proj + b_proj (fp32 out)
    gemm8<4, 0><<<dim3(M_ / 128, C_ / 256), 512, 0, stream>>>(
        aout, wprojT, b_proj, y, M_, C_, C_,
        nullptr, nullptr, nullptr, nullptr, nullptr, nullptr, nullptr);
}

// Round 8
// 227.542 us; speedup vs baseline: 1.1102x; 1.1102x over previous
//
#include <hip/hip_runtime.h>

typedef unsigned short u16;
typedef unsigned int u32;

#define B_    2
#define T_    2048
#define C_    2048
#define NH_   16
#define NKVH_ 4
#define HS_   128
#define NQKV  3072
#define M_    4096   // B*T
#define SCALE 0.08838834764831845f
#define CC    0.12751742f     // SCALE * log2(e)
#define THR_RAW 62.0f         // defer-max threshold (raw-score units, ~8/CC)

typedef __bf16 bf16x8 __attribute__((ext_vector_type(8)));
typedef float  f32x4  __attribute__((ext_vector_type(4)));
typedef float  f32x16 __attribute__((ext_vector_type(16)));
typedef unsigned int u32x2 __attribute__((ext_vector_type(2)));

__device__ __forceinline__ float bf2f(u16 u) {
    union { u32 i; float f; } x; x.i = ((u32)u) << 16; return x.f;
}
__device__ __forceinline__ u16 f2bf(float f) {
    union { float f; u32 i; } x; x.f = f;
    u32 r = x.i + 0x7fffu + ((x.i >> 16) & 1u);
    return (u16)(r >> 16);
}
__device__ __forceinline__ u32 pack2bf(float lo, float hi) {
    return (u32)f2bf(lo) | ((u32)f2bf(hi) << 16);
}
__device__ __forceinline__ u32 cvtpk(float lo, float hi) {
    u32 r; asm("v_cvt_pk_bf16_f32 %0, %1, %2" : "=v"(r) : "v"(lo), "v"(hi));
    return r;
}

// async global->LDS, 16B per lane; LDS dest = wave-uniform base + lane*16
__device__ __forceinline__ void gload16(const void* g, void* l) {
    __builtin_amdgcn_global_load_lds(
        (const __attribute__((address_space(1))) u32*)g,
        (__attribute__((address_space(3))) u32*)l,
        16, 0, 0);
}

// ---------------- cast x (f32 -> bf16) ----------------
__global__ __launch_bounds__(256) void cast_f32_bf16(
    const float* __restrict__ in, u16* __restrict__ out, int n)
{
    int idx = (blockIdx.x * 256 + threadIdx.x) * 4;
    if (idx < n) {
        float4 v = *reinterpret_cast<const float4*>(in + idx);
        u32 p0 = (u32)f2bf(v.x) | ((u32)f2bf(v.y) << 16);
        u32 p1 = (u32)f2bf(v.z) | ((u32)f2bf(v.w) << 16);
        u32* o = (u32*)(out + idx);
        o[0] = p0; o[1] = p1;
    }
}

// ---------------- transpose + cast (f32 RxC -> bf16 CxR) ----------------
__global__ __launch_bounds__(256) void transpose_cast_f32_bf16(
    const float* __restrict__ in, u16* __restrict__ out, int R, int Cc)
{
    __shared__ float tile[32][33];
    int c0 = blockIdx.x * 32, r0 = blockIdx.y * 32;
    int tx = threadIdx.x & 31, ty = threadIdx.x >> 5;  // 32 x 8
#pragma unroll
    for (int i = 0; i < 4; ++i)
        tile[ty + i * 8][tx] = in[(size_t)(r0 + ty + i * 8) * Cc + c0 + tx];
    __syncthreads();
#pragma unroll
    for (int i = 0; i < 4; ++i)
        out[(size_t)(c0 + ty + i * 8) * R + r0 + tx] = f2bf(tile[tx][ty + i * 8]);
}

// ---------------- batched bf16 transpose (z, R, Cc) -> (z, Cc, R) ----------------
__global__ __launch_bounds__(256) void transpose_bf16_batched(
    const u16* __restrict__ in, u16* __restrict__ out, int R, int Cc)
{
    __shared__ u16 tile[32][33];
    int c0 = blockIdx.x * 32, r0 = blockIdx.y * 32;
    size_t zb = (size_t)blockIdx.z * R * Cc;
    int tx = threadIdx.x & 31, ty = threadIdx.x >> 5;
#pragma unroll
    for (int i = 0; i < 4; ++i)
        tile[ty + i * 8][tx] = in[zb + (size_t)(r0 + ty + i * 8) * Cc + c0 + tx];
    __syncthreads();
#pragma unroll
    for (int i = 0; i < 4; ++i)
        out[zb + (size_t)(c0 + ty + i * 8) * R + r0 + tx] = tile[tx][ty + i * 8];
}

// ======== 8-phase MFMA GEMM: C[M,N] = A[M,K]*Bt[N,K]^T + bias ========
// Tile (MFRAG*32) x 256, 512 thr = 8 waves (2M x 4N), per-wave (MFRAG*16) x 64.
// BK=64, K-split halves (32k each). Quadrants q = (m-half, kk); register loads
// pipelined one phase ahead (only q0 stalls on lgkm). Stage points and
// vmcnt(2*LA+LB) ledger: tile kt+1 fully drained at kt's end-wait.
template <int MFRAG, int OUT_BF16>
__global__ __launch_bounds__(512, 2) void gemm8(
    const u16* __restrict__ A, const u16* __restrict__ Bt,
    const float* __restrict__ bias, void* __restrict__ Cv,
    int M, int N, int K)
{
    constexpr int MH = MFRAG / 2;       // m-frags per m-half
    constexpr int LA = MFRAG / 4;       // gload16 per A half-tile per wave
    constexpr int ASZ = MFRAG * 1024;   // elements per A half
    __shared__ __attribute__((aligned(16))) u16 As[2][2][ASZ];
    __shared__ __attribute__((aligned(16))) u16 Bs[2][2][8192];

    int tid = threadIdx.x, lane = tid & 63, w = tid >> 6;
    int l16 = lane & 15, hi = (lane >> 4) & 3;
    int wm = w >> 2, wn = w & 3;

    // bijective XCD swizzle (nwg % 8 == 0 for all our grids)
    int gx = gridDim.x, nwg = gx * gridDim.y;
    int id = blockIdx.y * gx + blockIdx.x;
    int nid = (id & 7) * (nwg >> 3) + (id >> 3);
    int brow = (nid % gx) * (MFRAG * 32), bcol = (nid / gx) * 256;

    const int NT = K >> 6;
    f32x4 acc[MFRAG][4] = {};

    auto stageA = [&](int kt2, int kk, int buf) {
#pragma unroll
        for (int i = 0; i < LA; ++i) {
            u32 off = (u32)i * 8192 + (u32)w * 1024 + ((u32)lane << 4);
            u32 g = off ^ (((off >> 7) & 7) << 4);
            u32 r = g >> 6, s = (g >> 4) & 3;
            gload16(A + (size_t)(brow + r) * K + kt2 * 64 + kk * 32 + s * 8,
                    (char*)&As[buf][kk][0] + i * 8192 + w * 1024);
        }
    };
    auto stageB = [&](int kt2, int kk, int buf) {
#pragma unroll
        for (int i = 0; i < 2; ++i) {
            u32 off = (u32)i * 8192 + (u32)w * 1024 + ((u32)lane << 4);
            u32 g = off ^ (((off >> 7) & 7) << 4);
            u32 r = g >> 6, s = (g >> 4) & 3;
            gload16(Bt + (size_t)(bcol + r) * K + kt2 * 64 + kk * 32 + s * 8,
                    (char*)&Bs[buf][kk][0] + i * 8192 + w * 1024);
        }
    };
    auto readA = [&](const u16* base, int mh, bf16x8* dst) {
#pragma unroll
        for (int m = 0; m < MH; ++m) {
            u32 a = (u32)((wm * MFRAG + mh * MH + m) * 16 + l16) * 64 + (u32)hi * 16;
            dst[m] = *reinterpret_cast<const bf16x8*>(
                (const char*)base + (a ^ (((a >> 7) & 7) << 4)));
        }
    };
    auto readB = [&](const u16* base, bf16x8* dst) {
#pragma unroll
        for (int n = 0; n < 4; ++n) {
            u32 a = (u32)(wn * 64 + n * 16 + l16) * 64 + (u32)hi * 16;
            dst[n] = *reinterpret_cast<const bf16x8*>(
                (const char*)base + (a ^ (((a >> 7) & 7) << 4)));
        }
    };

    // prologue: tile0 all 4 halves + tile1 {A0, B0, A1}; drain tile0
    stageA(0, 0, 0); stageB(0, 0, 0); stageA(0, 1, 0); stageB(0, 1, 0);
    if (NT > 1) {
        stageA(1, 0, 1); stageB(1, 0, 1); stageA(1, 1, 1);
        if constexpr (MFRAG == 8) asm volatile("s_waitcnt vmcnt(6)" ::: "memory");
        else                      asm volatile("s_waitcnt vmcnt(4)" ::: "memory");
    } else {
        asm volatile("s_waitcnt vmcnt(0)" ::: "memory");
    }
    __builtin_amdgcn_s_barrier();

    for (int kt = 0; kt < NT; ++kt) {
        int cur = kt & 1, nxt = cur ^ 1;
        const u16* Ac0 = &As[cur][0][0];
        const u16* Ac1 = &As[cur][1][0];
        const u16* Bc0 = &Bs[cur][0][0];
        const u16* Bc1 = &Bs[cur][1][0];
        bf16x8 af0[MH], af1[MH], af2[MH], af3[MH], bf0[4], bf1[4];

        // ---- P0: read q0+q1 operands (af0, bf0, af1); stage B1(kt+1) ----
        readA(Ac0, 0, af0); readB(Bc0, bf0); readA(Ac0, 1, af1);
        if (kt + 1 < NT) stageB(kt + 1, 1, nxt);
        __builtin_amdgcn_s_barrier();
        __builtin_amdgcn_s_setprio(1);
#pragma unroll
        for (int m = 0; m < MH; ++m)
#pragma unroll
            for (int n = 0; n < 4; ++n)
                acc[m][n] = __builtin_amdgcn_mfma_f32_16x16x32_bf16(
                    af0[m], bf0[n], acc[m][n], 0, 0, 0);
        __builtin_amdgcn_s_setprio(0);
        __builtin_amdgcn_s_barrier();

        // ---- P1: read q2 operands (af2, bf1); stage A0(kt+2) ----
        readA(Ac1, 0, af2); readB(Bc1, bf1);
        if (kt + 2 < NT) stageA(kt + 2, 0, cur);
        __builtin_amdgcn_s_barrier();
        __builtin_amdgcn_s_setprio(1);
#pragma unroll
        for (int m = 0; m < MH; ++m)
#pragma unroll
            for (int n = 0; n < 4; ++n)
                acc[MH + m][n] = __builtin_amdgcn_mfma_f32_16x16x32_bf16(
                    af1[m], bf0[n], acc[MH + m][n], 0, 0, 0);
        __builtin_amdgcn_s_setprio(0);
        __builtin_amdgcn_s_barrier();

        // ---- P2: read q3 operands (af3); stage B0(kt+2) ----
        readA(Ac1, 1, af3);
        if (kt + 2 < NT) stageB(kt + 2, 0, cur);
        __builtin_amdgcn_s_barrier();
        __builtin_amdgcn_s_setprio(1);
#pragma unroll
        for (int m = 0; m < MH; ++m)
#pragma unroll
            for (int n = 0; n < 4; ++n)
                acc[m][n] = __builtin_amdgcn_mfma_f32_16x16x32_bf16(
                    af2[m], bf1[n], acc[m][n], 0, 0, 0);
        __builtin_amdgcn_s_setprio(0);
        __builtin_amdgcn_s_barrier();

        // ---- P3: stage A1(kt+2); end-of-tile counted wait ----
        if (kt + 2 < NT) stageA(kt + 2, 1, cur);
        __builtin_amdgcn_s_barrier();
        __builtin_amdgcn_s_setprio(1);
#pragma unroll
        for (int m = 0; m < MH; ++m)
#pragma unroll
            for (int n = 0; n < 4; ++n)
                acc[MH + m][n] = __builtin_amdgcn_mfma_f32_16x16x32_bf16(
                    af3[m], bf1[n], acc[MH + m][n], 0, 0, 0);
        __builtin_amdgcn_s_setprio(0);
        if (kt + 1 < NT) {
            if (kt + 2 < NT) {
                if constexpr (MFRAG == 8) asm volatile("s_waitcnt vmcnt(6)" ::: "memory");
                else                      asm volatile("s_waitcnt vmcnt(4)" ::: "memory");
            } else {
                asm volatile("s_waitcnt vmcnt(0)" ::: "memory");
            }
        }
        __builtin_amdgcn_s_barrier();
    }

    // ---- epilogue ----
#pragma unroll
    for (int n = 0; n < 4; ++n) {
        int col = bcol + wn * 64 + n * 16 + l16;
        float bv = bias[col];
#pragma unroll
        for (int m = 0; m < MFRAG; ++m) {
#pragma unroll
            for (int j = 0; j < 4; ++j) {
                int row = brow + wm * (MFRAG * 16) + m * 16 + hi * 4 + j;
                float v = acc[m][n][j] + bv;
                if (OUT_BF16)
                    ((u16*)Cv)[(size_t)row * N + col] = f2bf(v);
                else
                    ((float*)Cv)[(size_t)row * N + col] = v;
            }
        }
    }
}

// ---------------- RoPE + scatter q/k/v (u32/float2 vectorized) ----------------
__global__ __launch_bounds__(256) void rope_scatter(
    const u16* __restrict__ qkv,
    const float* __restrict__ fcos, const float* __restrict__ fsin,
    u16* __restrict__ qb, u16* __restrict__ kb, u16* __restrict__ vb,
    float* __restrict__ kc, float* __restrict__ vc)
{
    int bt = blockIdx.x;
    int b = bt >> 11, t = bt & 2047;
    const u16* row = qkv + (size_t)bt * NQKV;
#pragma unroll
    for (int s = threadIdx.x; s < NQKV / 2; s += 256) {
        int col = s * 2;
        u32 pair = *reinterpret_cast<const u32*>(row + col);
        float xr = bf2f((u16)pair), xi = bf2f((u16)(pair >> 16));
        if (col < C_) {                       // q
            int h = col >> 7, d = col & 127;
            int fi = t * 64 + (d >> 1);
            float c = fcos[fi], sn = fsin[fi];
            size_t o = ((size_t)(b * NH_ + h) * T_ + t) * HS_ + d;
            *reinterpret_cast<u32*>(qb + o) =
                pack2bf(xr * c - xi * sn, xr * sn + xi * c);
        } else if (col < C_ + NKVH_ * HS_) {  // k
            int cc = col - C_;
            int h = cc >> 7, d = cc & 127;
            int fi = t * 64 + (d >> 1);
            float c = fcos[fi], sn = fsin[fi];
            float yr = xr * c - xi * sn, yi = xr * sn + xi * c;
            size_t o = ((size_t)(b * NKVH_ + h) * T_ + t) * HS_ + d;
            *reinterpret_cast<u32*>(kb + o) = pack2bf(yr, yi);
            *reinterpret_cast<float2*>(kc + o) = make_float2(yr, yi);
        } else {                               // v
            int cc = col - (C_ + NKVH_ * HS_);
            int h = cc >> 7, d = cc & 127;
            size_t o = ((size_t)(b * NKVH_ + h) * T_ + t) * HS_ + d;
            *reinterpret_cast<u32*>(vb + o) = pair;
            *reinterpret_cast<float2*>(vc + o) = make_float2(xr, xi);
        }
    }
}

// ---------------- flash attention (causal, GQA), 32x32 swapped-QK ----------------
// R4-verified form (85.0 us): QBLK=128 (4 waves x 32 q-rows), KVBLK=64,
// K/V dbuf + XOR-swizzle, sum-15 co-resident pairing, NO setprio (-5% measured).
#define STAGE_KV(it_, buf_)                                               \
  {                                                                       \
    int _it = (it_);                                                      \
    _Pragma("unroll")                                                     \
    for (int i = 0; i < 4; ++i) {                                         \
      int chunk = w * 4 + i;                                              \
      int rk = chunk * 4 + (lane >> 4);                                   \
      int ck = ((lane & 15) ^ (rk & 7)) << 3;                             \
      gload16(Kp + (size_t)(_it * 64 + rk) * HS_ + ck,                    \
              (char*)Ks[buf_] + chunk * 1024);                            \
      int rv = chunk * 8 + (lane >> 3);                                   \
      int cv = ((lane & 7) ^ (rv & 7)) << 3;                              \
      gload16(Vp + (size_t)rv * T_ + _it * 64 + cv,                       \
              (char*)Vs[buf_] + chunk * 1024);                            \
    }                                                                     \
  }

__global__ __launch_bounds__(256, 2) void attn_kernel(
    const u16* __restrict__ qb,   // (B, NH, T, HS)
    const u16* __restrict__ kb,   // (B, NKVH, T, HS)
    const u16* __restrict__ vt,   // (B, NKVH, HS, T)
    u16* __restrict__ aout)       // (B, T, C) bf16
{
    __shared__ __attribute__((aligned(16))) u16 Ks[2][64 * 128];
    __shared__ __attribute__((aligned(16))) u16 Vs[2][128 * 64];

    // load-balance remap: co-resident pair (n, n+256) gets qt summing to 15
    int xx = blockIdx.x, yy = blockIdx.y;
    int qt = (yy < 16) ? (15 - xx) : xx;
    int bh = yy, b = bh >> 4, h = bh & 15, kvh = h >> 2;
    int lane = threadIdx.x & 63, w = threadIdx.x >> 6;
    int l32 = lane & 31, l5 = lane >> 5;
    int xorm = (l32 & 7) << 3;               // element-space XOR for LDS reads
    int koff = 8 * l5;

    const u16* Qp = qb + ((size_t)(b * NH_ + h) * T_ + qt * 128 + w * 32) * HS_;
    const u16* Kp = kb + (size_t)(b * NKVH_ + kvh) * T_ * HS_;
    const u16* Vp = vt + (size_t)(b * NKVH_ + kvh) * HS_ * T_;

    // Q as B-operand frags: row = l32 (q), k = kd*16 + 8*l5 + [0..7]
    bf16x8 qf[8];
#pragma unroll
    for (int kd = 0; kd < 8; ++kd)
        qf[kd] = *reinterpret_cast<const bf16x8*>(
            Qp + (size_t)l32 * HS_ + kd * 16 + koff);

    f32x16 o[4] = {};
    float m = -1e30f, lrow = 0.f;
    int qg = qt * 128 + w * 32 + l32;        // this lane's q row
    int qmaxw = qt * 128 + w * 32 + 31;

    int ntiles = 2 * qt + 2;
    STAGE_KV(0, 0);

    for (int it = 0; it < ntiles; ++it) {
        int buf = it & 1;
        __syncthreads();                     // tile `it` resident
        if (it + 1 < ntiles) STAGE_KV(it + 1, buf ^ 1);

        if (it * 64 <= qmaxw) {              // wave has unmasked work here
            const u16* Kbase = Ks[buf];
            const u16* Vbase = Vs[buf];

            // ---- S = K Q^T : D[kv][q], q = l32 lane-local ----
            f32x16 sacc[2] = {};
#pragma unroll
            for (int kt2 = 0; kt2 < 2; ++kt2)
#pragma unroll
                for (int kd = 0; kd < 8; ++kd) {
                    bf16x8 kf = *reinterpret_cast<const bf16x8*>(
                        Kbase + (kt2 * 32 + l32) * 128 + ((kd * 16 + koff) ^ xorm));
                    sacc[kt2] = __builtin_amdgcn_mfma_f32_32x32x16_bf16(
                        kf, qf[kd], sacc[kt2], 0, 0, 0);
                }

            // ---- causal mask (raw scores; exp folds the scale) ----
            if (it * 64 + 63 > qt * 128 + w * 32) {
#pragma unroll
                for (int kt2 = 0; kt2 < 2; ++kt2)
#pragma unroll
                    for (int r = 0; r < 16; ++r) {
                        int kvg = it * 64 + kt2 * 32 + (r & 3) + 8 * (r >> 2) + 4 * l5;
                        if (kvg > qg) sacc[kt2][r] = -1e30f;
                    }
            }

            // ---- row max (tree + 1 cross-half shuffle) ----
            float mx;
            {
                float t8[8];
#pragma unroll
                for (int i = 0; i < 8; ++i) {
                    float a = fmaxf(sacc[0][i], sacc[0][i + 8]);
                    float c = fmaxf(sacc[1][i], sacc[1][i + 8]);
                    t8[i] = fmaxf(a, c);
                }
                float t4a = fmaxf(t8[0], t8[1]), t4b = fmaxf(t8[2], t8[3]);
                float t4c = fmaxf(t8[4], t8[5]), t4d = fmaxf(t8[6], t8[7]);
                mx = fmaxf(fmaxf(t4a, t4b), fmaxf(t4c, t4d));
                mx = fmaxf(mx, __shfl_xor(mx, 32));
            }

            // ---- defer-max: rescale only when max grew past threshold ----
            if (!__all(mx <= m + THR_RAW)) {
                float nm = fmaxf(m, mx);
                float al = exp2f(CC * (m - nm));
                m = nm;
                lrow *= al;
#pragma unroll
                for (int r = 0; r < 16; ++r) {
                    float af = __shfl(al, (r & 3) + 8 * (r >> 2) + 4 * l5, 64);
                    o[0][r] *= af; o[1][r] *= af; o[2][r] *= af; o[3][r] *= af;
                }
            }
            float mcm = -CC * m;

            // ---- P = 2^(CC*s - CC*m), row sum ----
            f32x16 p[2];
#pragma unroll
            for (int kt2 = 0; kt2 < 2; ++kt2)
#pragma unroll
                for (int r = 0; r < 16; ++r)
                    p[kt2][r] = exp2f(__builtin_fmaf(CC, sacc[kt2][r], mcm));
            {
                float s8[8];
#pragma unroll
                for (int i = 0; i < 8; ++i)
                    s8[i] = (p[0][i] + p[0][i + 8]) + (p[1][i] + p[1][i + 8]);
                float s4a = s8[0] + s8[1], s4b = s8[2] + s8[3];
                float s4c = s8[4] + s8[5], s4d = s8[6] + s8[7];
                float rs = (s4a + s4b) + (s4c + s4d);
                rs += __shfl_xor(rs, 32);
                lrow += rs;
            }

            // ---- PV: build A-frags in-register (cvt_pk + permlane32_swap) ----
#pragma unroll
            for (int ks = 0; ks < 4; ++ks) {
                int e = ks & 1, kh = ks >> 1;
                u32 a0 = cvtpk(p[kh][8 * e + 0], p[kh][8 * e + 1]);
                u32 a1 = cvtpk(p[kh][8 * e + 2], p[kh][8 * e + 3]);
                u32 b0 = cvtpk(p[kh][8 * e + 4], p[kh][8 * e + 5]);
                u32 b1 = cvtpk(p[kh][8 * e + 6], p[kh][8 * e + 7]);
                u32x2 s0 = __builtin_amdgcn_permlane32_swap(a0, b0, false, false);
                u32x2 s1 = __builtin_amdgcn_permlane32_swap(a1, b1, false, false);
                union { u32 u[4]; bf16x8 v; } pu;
                pu.u[0] = s0[0]; pu.u[1] = s1[0]; pu.u[2] = s0[1]; pu.u[3] = s1[1];
                bf16x8 pf = pu.v;
#pragma unroll
                for (int dt = 0; dt < 4; ++dt) {
                    bf16x8 vf = *reinterpret_cast<const bf16x8*>(
                        Vbase + (dt * 32 + l32) * 64 + ((ks * 16 + koff) ^ xorm));
                    o[dt] = __builtin_amdgcn_mfma_f32_32x32x16_bf16(
                        pf, vf, o[dt], 0, 0, 0);
                }
            }
        }
    }

    // ---- epilogue: normalize (broadcast 1/l to reg-dim) and store ----
    float inv = 1.0f / lrow;
#pragma unroll
    for (int r = 0; r < 16; ++r) {
        int ql = (r & 3) + 8 * (r >> 2) + 4 * l5;
        float iv = __shfl(inv, ql, 64);
        int trow = qt * 128 + w * 32 + ql;
        size_t base = ((size_t)b * T_ + trow) * C_ + h * HS_ + l32;
#pragma unroll
        for (int dt = 0; dt < 4; ++dt)
            aout[base + dt * 32] = f2bf(o[dt][r] * iv);
    }
}

// ---------------- launch ----------------
extern "C" void kernel_launch(void* const* d_in, const int* in_sizes, int n_in,
                              void* d_out, int out_size, void* d_ws, size_t ws_size,
                              hipStream_t stream)
{
    const float* x      = (const float*)d_in[0];
    const float* w_qkv  = (const float*)d_in[1];
    const float* b_qkv  = (const float*)d_in[2];
    const float* w_proj = (const float*)d_in[3];
    const float* b_proj = (const float*)d_in[4];
    const float* fcos   = (const float*)d_in[5];
    const float* fsin   = (const float*)d_in[6];

    float* y  = (float*)d_out;
    float* kc = y + (size_t)B_ * T_ * C_;
    float* vc = kc + (size_t)B_ * NKVH_ * T_ * HS_;

    // R5-proven workspace layout (71.3 MB)
    char* ws = (char*)d_ws;
    u16* xb     = (u16*)(ws);
    u16* wprojT = (u16*)(ws);
    u16* wqkvT = (u16*)(ws + 16777216);
    u16* kbuf  = (u16*)(ws + 16777216);
    u16* vbuf  = (u16*)(ws + 16777216 + 4194304);
    u16* vtb   = (u16*)(ws + 16777216 + 8388608);
    u16* qkv  = (u16*)(ws + 29360128);
    u16* aout = (u16*)(ws + 29360128);
    u16* qbuf = (u16*)(ws + 54525952);

    cast_f32_bf16<<<M_ * C_ / 1024, 256, 0, stream>>>(x, xb, M_ * C_);
    transpose_cast_f32_bf16<<<dim3(NQKV / 32, C_ / 32), 256, 0, stream>>>(
        w_qkv, wqkvT, C_, NQKV);
    gemm8<8, 1><<<dim3(M_ / 256, NQKV / 256), 512, 0, stream>>>(
        xb, wqkvT, b_qkv, qkv, M_, NQKV, C_);
    rope_scatter<<<M_, 256, 0, stream>>>(qkv, fcos, fsin, qbuf, kbuf, vbuf, kc, vc);
    transpose_bf16_batched<<<dim3(HS_ / 32, T_ / 32, B_ * NKVH_), 256, 0, stream>>>(
        vbuf, vtb, T_, HS_);
    transpose_cast_f32_bf16<<<dim3(C_ / 32, C_ / 32), 256, 0, stream>>>(
        w_proj, wprojT, C_, C_);
    attn_kernel<<<dim3(T_ / 128, B_ * NH_), 256, 0, stream>>>(qbuf, kbuf, vtb, aout);
    gemm8<4, 0><<<dim3(M_ / 128, C_ / 256), 512, 0, stream>>>(
        aout, wprojT, b_proj, y, M_, C_, C_);
}

// Round 9
// 224.091 us; speedup vs baseline: 1.1273x; 1.0154x over previous
//
#include <hip/hip_runtime.h>

typedef unsigned short u16;
typedef unsigned int u32;

#define B_    2
#define T_    2048
#define C_    2048
#define NH_   16
#define NKVH_ 4
#define HS_   128
#define NQKV  3072
#define M_    4096   // B*T
#define SCALE 0.08838834764831845f
#define CC    0.12751742f     // SCALE * log2(e)
#define THR_RAW 62.0f         // defer-max threshold (raw-score units, ~8/CC)

typedef __bf16 bf16x8 __attribute__((ext_vector_type(8)));
typedef float  f32x4  __attribute__((ext_vector_type(4)));
typedef float  f32x16 __attribute__((ext_vector_type(16)));
typedef unsigned int u32x2 __attribute__((ext_vector_type(2)));

__device__ __forceinline__ float bf2f(u16 u) {
    union { u32 i; float f; } x; x.i = ((u32)u) << 16; return x.f;
}
__device__ __forceinline__ u16 f2bf(float f) {
    union { float f; u32 i; } x; x.f = f;
    u32 r = x.i + 0x7fffu + ((x.i >> 16) & 1u);
    return (u16)(r >> 16);
}
__device__ __forceinline__ u32 pack2bf(float lo, float hi) {
    return (u32)f2bf(lo) | ((u32)f2bf(hi) << 16);
}
__device__ __forceinline__ u32 cvtpk(float lo, float hi) {
    u32 r; asm("v_cvt_pk_bf16_f32 %0, %1, %2" : "=v"(r) : "v"(lo), "v"(hi));
    return r;
}

// async global->LDS, 16B per lane; LDS dest = wave-uniform base + lane*16
__device__ __forceinline__ void gload16(const void* g, void* l) {
    __builtin_amdgcn_global_load_lds(
        (const __attribute__((address_space(1))) u32*)g,
        (__attribute__((address_space(3))) u32*)l,
        16, 0, 0);
}

// ---------------- cast x (f32 -> bf16) ----------------
__global__ __launch_bounds__(256) void cast_f32_bf16(
    const float* __restrict__ in, u16* __restrict__ out, int n)
{
    int idx = (blockIdx.x * 256 + threadIdx.x) * 4;
    if (idx < n) {
        float4 v = *reinterpret_cast<const float4*>(in + idx);
        u32 p0 = (u32)f2bf(v.x) | ((u32)f2bf(v.y) << 16);
        u32 p1 = (u32)f2bf(v.z) | ((u32)f2bf(v.w) << 16);
        u32* o = (u32*)(out + idx);
        o[0] = p0; o[1] = p1;
    }
}

// ---------------- transpose + cast (f32 RxC -> bf16 CxR) ----------------
__global__ __launch_bounds__(256) void transpose_cast_f32_bf16(
    const float* __restrict__ in, u16* __restrict__ out, int R, int Cc)
{
    __shared__ float tile[32][33];
    int c0 = blockIdx.x * 32, r0 = blockIdx.y * 32;
    int tx = threadIdx.x & 31, ty = threadIdx.x >> 5;  // 32 x 8
#pragma unroll
    for (int i = 0; i < 4; ++i)
        tile[ty + i * 8][tx] = in[(size_t)(r0 + ty + i * 8) * Cc + c0 + tx];
    __syncthreads();
#pragma unroll
    for (int i = 0; i < 4; ++i)
        out[(size_t)(c0 + ty + i * 8) * R + r0 + tx] = f2bf(tile[tx][ty + i * 8]);
}

// ---------------- batched bf16 transpose (z, R, Cc) -> (z, Cc, R) ----------------
__global__ __launch_bounds__(256) void transpose_bf16_batched(
    const u16* __restrict__ in, u16* __restrict__ out, int R, int Cc)
{
    __shared__ u16 tile[32][33];
    int c0 = blockIdx.x * 32, r0 = blockIdx.y * 32;
    size_t zb = (size_t)blockIdx.z * R * Cc;
    int tx = threadIdx.x & 31, ty = threadIdx.x >> 5;
#pragma unroll
    for (int i = 0; i < 4; ++i)
        tile[ty + i * 8][tx] = in[zb + (size_t)(r0 + ty + i * 8) * Cc + c0 + tx];
    __syncthreads();
#pragma unroll
    for (int i = 0; i < 4; ++i)
        out[zb + (size_t)(c0 + ty + i * 8) * R + r0 + tx] = tile[tx][ty + i * 8];
}

// ======== 8-phase MFMA GEMM: C[M,N] = A[M,K]*Bt[N,K]^T + bias ========
// R8 schedule (barriers/vmcnt ledger identical), with addressing hoisted:
// lane-constant swizzled LDS bases + compile-time buffer/kk (K-loop unrolled
// by 2) so all ds_read offsets fold into immediates; global staging bases
// precomputed, advanced by immediate (kt2<<6 elements).
#define STA(KT2, KK, BUF)                                                  \
  { _Pragma("unroll") for (int i_ = 0; i_ < LA; ++i_)                      \
      gload16(gA[i_] + ((KT2) << 6) + (KK) * 32,                           \
              (char*)&As[BUF][KK][0] + i_ * 8192 + w * 1024); }
#define STB(KT2, KK, BUF)                                                  \
  { _Pragma("unroll") for (int i_ = 0; i_ < 2; ++i_)                       \
      gload16(gB[i_] + ((KT2) << 6) + (KK) * 32,                           \
              (char*)&Bs[BUF][KK][0] + i_ * 8192 + w * 1024); }
#define RDA(DST, BUF, KK, MHALF)                                           \
  { _Pragma("unroll") for (int m_ = 0; m_ < MH; ++m_)                      \
      DST[m_] = *reinterpret_cast<const bf16x8*>(                          \
          aLane + ((BUF) * 2 + (KK)) * ABLKB + ((MHALF) * MH + m_) * 1024); }
#define RDB(DST, BUF, KK)                                                  \
  { _Pragma("unroll") for (int n_ = 0; n_ < 4; ++n_)                       \
      DST[n_] = *reinterpret_cast<const bf16x8*>(                          \
          bLane + ((BUF) * 2 + (KK)) * 16384 + n_ * 1024); }
#define KBODY(KT, CUR)                                                     \
  {                                                                        \
    const int kt_ = (KT);                                                  \
    bf16x8 af0[MH], af1[MH], af2[MH], af3[MH], bf0[4], bf1[4];             \
    RDA(af0, CUR, 0, 0); RDB(bf0, CUR, 0); RDA(af1, CUR, 0, 1);            \
    if (kt_ + 1 < NT) STB(kt_ + 1, 1, CUR ^ 1);                            \
    __builtin_amdgcn_s_barrier();                                          \
    __builtin_amdgcn_s_setprio(1);                                         \
    _Pragma("unroll") for (int m = 0; m < MH; ++m)                         \
      _Pragma("unroll") for (int n = 0; n < 4; ++n)                        \
        acc[m][n] = __builtin_amdgcn_mfma_f32_16x16x32_bf16(               \
            af0[m], bf0[n], acc[m][n], 0, 0, 0);                           \
    __builtin_amdgcn_s_setprio(0);                                         \
    __builtin_amdgcn_s_barrier();                                          \
    RDA(af2, CUR, 1, 0); RDB(bf1, CUR, 1);                                 \
    if (kt_ + 2 < NT) STA(kt_ + 2, 0, CUR);                                \
    __builtin_amdgcn_s_barrier();                                          \
    __builtin_amdgcn_s_setprio(1);                                         \
    _Pragma("unroll") for (int m = 0; m < MH; ++m)                         \
      _Pragma("unroll") for (int n = 0; n < 4; ++n)                        \
        acc[MH + m][n] = __builtin_amdgcn_mfma_f32_16x16x32_bf16(          \
            af1[m], bf0[n], acc[MH + m][n], 0, 0, 0);                      \
    __builtin_amdgcn_s_setprio(0);                                         \
    __builtin_amdgcn_s_barrier();                                          \
    RDA(af3, CUR, 1, 1);                                                   \
    if (kt_ + 2 < NT) STB(kt_ + 2, 0, CUR);                                \
    __builtin_amdgcn_s_barrier();                                          \
    __builtin_amdgcn_s_setprio(1);                                         \
    _Pragma("unroll") for (int m = 0; m < MH; ++m)                         \
      _Pragma("unroll") for (int n = 0; n < 4; ++n)                        \
        acc[m][n] = __builtin_amdgcn_mfma_f32_16x16x32_bf16(               \
            af2[m], bf1[n], acc[m][n], 0, 0, 0);                           \
    __builtin_amdgcn_s_setprio(0);                                         \
    __builtin_amdgcn_s_barrier();                                          \
    if (kt_ + 2 < NT) STA(kt_ + 2, 1, CUR);                                \
    __builtin_amdgcn_s_barrier();                                          \
    __builtin_amdgcn_s_setprio(1);                                         \
    _Pragma("unroll") for (int m = 0; m < MH; ++m)                         \
      _Pragma("unroll") for (int n = 0; n < 4; ++n)                        \
        acc[MH + m][n] = __builtin_amdgcn_mfma_f32_16x16x32_bf16(          \
            af3[m], bf1[n], acc[MH + m][n], 0, 0, 0);                      \
    __builtin_amdgcn_s_setprio(0);                                         \
    if (kt_ + 1 < NT) {                                                    \
      if (kt_ + 2 < NT) {                                                  \
        if constexpr (MFRAG == 8)                                          \
          asm volatile("s_waitcnt vmcnt(6)" ::: "memory");                 \
        else                                                               \
          asm volatile("s_waitcnt vmcnt(4)" ::: "memory");                 \
      } else {                                                             \
        asm volatile("s_waitcnt vmcnt(0)" ::: "memory");                   \
      }                                                                    \
    }                                                                      \
    __builtin_amdgcn_s_barrier();                                          \
  }

template <int MFRAG, int OUT_BF16>
__global__ __launch_bounds__(512, 2) void gemm8(
    const u16* __restrict__ A, const u16* __restrict__ Bt,
    const float* __restrict__ bias, void* __restrict__ Cv,
    int M, int N, int K)
{
    constexpr int MH = MFRAG / 2;        // m-frags per m-half
    constexpr int LA = MFRAG / 4;        // gload16 per A half-tile per wave
    constexpr int ABLKB = MFRAG * 2048;  // bytes per As[buf][kk] block
    __shared__ __attribute__((aligned(16))) u16 As[2][2][MFRAG * 1024];
    __shared__ __attribute__((aligned(16))) u16 Bs[2][2][8192];

    int tid = threadIdx.x, lane = tid & 63, w = tid >> 6;
    int l16 = lane & 15, hi = (lane >> 4) & 3;
    int wm = w >> 2, wn = w & 3;

    // bijective XCD swizzle (nwg % 8 == 0 for all our grids)
    int gx = gridDim.x, nwg = gx * gridDim.y;
    int id = blockIdx.y * gx + blockIdx.x;
    int nid = (id & 7) * (nwg >> 3) + (id >> 3);
    int brow = (nid % gx) * (MFRAG * 32), bcol = (nid / gx) * 256;

    const int NT = K >> 6;
    f32x4 acc[MFRAG][4] = {};

    // ---- hoisted lane-constant addressing ----
    // LDS read: byte addr within block = row16*1024 + (l16*64 + hi*16)^swz;
    // the XOR term ((a>>7)&7)<<4 depends only on l16 -> lane-constant.
    u32 abase = (u32)l16 * 64 + (u32)hi * 16;
    u32 aoff  = abase ^ (((abase >> 7) & 7) << 4);
    const char* aLane = (const char*)&As[0][0][0] + wm * (MFRAG * 1024) + aoff;
    const char* bLane = (const char*)&Bs[0][0][0] + wn * 4096 + aoff;

    // global staging bases (row/subcol swizzle lane-constant, kt folds to imm)
    const u16* gA[LA];
    const u16* gB[2];
#pragma unroll
    for (int i = 0; i < LA; ++i) {
        u32 off = (u32)i * 8192 + (u32)w * 1024 + ((u32)lane << 4);
        u32 g = off ^ (((off >> 7) & 7) << 4);
        gA[i] = A + (size_t)(brow + (g >> 6)) * K + ((g >> 4) & 3) * 8;
    }
#pragma unroll
    for (int i = 0; i < 2; ++i) {
        u32 off = (u32)i * 8192 + (u32)w * 1024 + ((u32)lane << 4);
        u32 g = off ^ (((off >> 7) & 7) << 4);
        gB[i] = Bt + (size_t)(bcol + (g >> 6)) * K + ((g >> 4) & 3) * 8;
    }

    // prologue: tile0 all 4 halves + tile1 {A0, B0, A1}; drain tile0
    STA(0, 0, 0); STB(0, 0, 0); STA(0, 1, 0); STB(0, 1, 0);
    if (NT > 1) {
        STA(1, 0, 1); STB(1, 0, 1); STA(1, 1, 1);
        if constexpr (MFRAG == 8) asm volatile("s_waitcnt vmcnt(6)" ::: "memory");
        else                      asm volatile("s_waitcnt vmcnt(4)" ::: "memory");
    } else {
        asm volatile("s_waitcnt vmcnt(0)" ::: "memory");
    }
    __builtin_amdgcn_s_barrier();

    for (int kt = 0; kt < NT; kt += 2) {   // NT even (K=2048)
        KBODY(kt, 0);
        KBODY(kt + 1, 1);
    }

    // ---- epilogue ----
#pragma unroll
    for (int n = 0; n < 4; ++n) {
        int col = bcol + wn * 64 + n * 16 + l16;
        float bv = bias[col];
#pragma unroll
        for (int m = 0; m < MFRAG; ++m) {
#pragma unroll
            for (int j = 0; j < 4; ++j) {
                int row = brow + wm * (MFRAG * 16) + m * 16 + hi * 4 + j;
                float v = acc[m][n][j] + bv;
                if (OUT_BF16)
                    ((u16*)Cv)[(size_t)row * N + col] = f2bf(v);
                else
                    ((float*)Cv)[(size_t)row * N + col] = v;
            }
        }
    }
}
#undef STA
#undef STB
#undef RDA
#undef RDB
#undef KBODY

// ---------------- RoPE + scatter q/k/v (u32/float2 vectorized) ----------------
__global__ __launch_bounds__(256) void rope_scatter(
    const u16* __restrict__ qkv,
    const float* __restrict__ fcos, const float* __restrict__ fsin,
    u16* __restrict__ qb, u16* __restrict__ kb, u16* __restrict__ vb,
    float* __restrict__ kc, float* __restrict__ vc)
{
    int bt = blockIdx.x;
    int b = bt >> 11, t = bt & 2047;
    const u16* row = qkv + (size_t)bt * NQKV;
#pragma unroll
    for (int s = threadIdx.x; s < NQKV / 2; s += 256) {
        int col = s * 2;
        u32 pair = *reinterpret_cast<const u32*>(row + col);
        float xr = bf2f((u16)pair), xi = bf2f((u16)(pair >> 16));
        if (col < C_) {                       // q
            int h = col >> 7, d = col & 127;
            int fi = t * 64 + (d >> 1);
            float c = fcos[fi], sn = fsin[fi];
            size_t o = ((size_t)(b * NH_ + h) * T_ + t) * HS_ + d;
            *reinterpret_cast<u32*>(qb + o) =
                pack2bf(xr * c - xi * sn, xr * sn + xi * c);
        } else if (col < C_ + NKVH_ * HS_) {  // k
            int cc = col - C_;
            int h = cc >> 7, d = cc & 127;
            int fi = t * 64 + (d >> 1);
            float c = fcos[fi], sn = fsin[fi];
            float yr = xr * c - xi * sn, yi = xr * sn + xi * c;
            size_t o = ((size_t)(b * NKVH_ + h) * T_ + t) * HS_ + d;
            *reinterpret_cast<u32*>(kb + o) = pack2bf(yr, yi);
            *reinterpret_cast<float2*>(kc + o) = make_float2(yr, yi);
        } else {                               // v
            int cc = col - (C_ + NKVH_ * HS_);
            int h = cc >> 7, d = cc & 127;
            size_t o = ((size_t)(b * NKVH_ + h) * T_ + t) * HS_ + d;
            *reinterpret_cast<u32*>(vb + o) = pair;
            *reinterpret_cast<float2*>(vc + o) = make_float2(xr, xi);
        }
    }
}

// ---------------- flash attention (causal, GQA), 32x32 swapped-QK ----------------
// R4-verified form (85.0 us): QBLK=128 (4 waves x 32 q-rows), KVBLK=64,
// K/V dbuf + XOR-swizzle, sum-15 co-resident pairing, NO setprio (-5% measured).
#define STAGE_KV(it_, buf_)                                               \
  {                                                                       \
    int _it = (it_);                                                      \
    _Pragma("unroll")                                                     \
    for (int i = 0; i < 4; ++i) {                                         \
      int chunk = w * 4 + i;                                              \
      int rk = chunk * 4 + (lane >> 4);                                   \
      int ck = ((lane & 15) ^ (rk & 7)) << 3;                             \
      gload16(Kp + (size_t)(_it * 64 + rk) * HS_ + ck,                    \
              (char*)Ks[buf_] + chunk * 1024);                            \
      int rv = chunk * 8 + (lane >> 3);                                   \
      int cv = ((lane & 7) ^ (rv & 7)) << 3;                              \
      gload16(Vp + (size_t)rv * T_ + _it * 64 + cv,                       \
              (char*)Vs[buf_] + chunk * 1024);                            \
    }                                                                     \
  }

__global__ __launch_bounds__(256, 2) void attn_kernel(
    const u16* __restrict__ qb,   // (B, NH, T, HS)
    const u16* __restrict__ kb,   // (B, NKVH, T, HS)
    const u16* __restrict__ vt,   // (B, NKVH, HS, T)
    u16* __restrict__ aout)       // (B, T, C) bf16
{
    __shared__ __attribute__((aligned(16))) u16 Ks[2][64 * 128];
    __shared__ __attribute__((aligned(16))) u16 Vs[2][128 * 64];

    // load-balance remap: co-resident pair (n, n+256) gets qt summing to 15
    int xx = blockIdx.x, yy = blockIdx.y;
    int qt = (yy < 16) ? (15 - xx) : xx;
    int bh = yy, b = bh >> 4, h = bh & 15, kvh = h >> 2;
    int lane = threadIdx.x & 63, w = threadIdx.x >> 6;
    int l32 = lane & 31, l5 = lane >> 5;
    int xorm = (l32 & 7) << 3;               // element-space XOR for LDS reads
    int koff = 8 * l5;

    const u16* Qp = qb + ((size_t)(b * NH_ + h) * T_ + qt * 128 + w * 32) * HS_;
    const u16* Kp = kb + (size_t)(b * NKVH_ + kvh) * T_ * HS_;
    const u16* Vp = vt + (size_t)(b * NKVH_ + kvh) * HS_ * T_;

    // Q as B-operand frags: row = l32 (q), k = kd*16 + 8*l5 + [0..7]
    bf16x8 qf[8];
#pragma unroll
    for (int kd = 0; kd < 8; ++kd)
        qf[kd] = *reinterpret_cast<const bf16x8*>(
            Qp + (size_t)l32 * HS_ + kd * 16 + koff);

    f32x16 o[4] = {};
    float m = -1e30f, lrow = 0.f;
    int qg = qt * 128 + w * 32 + l32;        // this lane's q row
    int qmaxw = qt * 128 + w * 32 + 31;

    int ntiles = 2 * qt + 2;
    STAGE_KV(0, 0);

    for (int it = 0; it < ntiles; ++it) {
        int buf = it & 1;
        __syncthreads();                     // tile `it` resident
        if (it + 1 < ntiles) STAGE_KV(it + 1, buf ^ 1);

        if (it * 64 <= qmaxw) {              // wave has unmasked work here
            const u16* Kbase = Ks[buf];
            const u16* Vbase = Vs[buf];

            // ---- S = K Q^T : D[kv][q], q = l32 lane-local ----
            f32x16 sacc[2] = {};
#pragma unroll
            for (int kt2 = 0; kt2 < 2; ++kt2)
#pragma unroll
                for (int kd = 0; kd < 8; ++kd) {
                    bf16x8 kf = *reinterpret_cast<const bf16x8*>(
                        Kbase + (kt2 * 32 + l32) * 128 + ((kd * 16 + koff) ^ xorm));
                    sacc[kt2] = __builtin_amdgcn_mfma_f32_32x32x16_bf16(
                        kf, qf[kd], sacc[kt2], 0, 0, 0);
                }

            // ---- causal mask (raw scores; exp folds the scale) ----
            if (it * 64 + 63 > qt * 128 + w * 32) {
#pragma unroll
                for (int kt2 = 0; kt2 < 2; ++kt2)
#pragma unroll
                    for (int r = 0; r < 16; ++r) {
                        int kvg = it * 64 + kt2 * 32 + (r & 3) + 8 * (r >> 2) + 4 * l5;
                        if (kvg > qg) sacc[kt2][r] = -1e30f;
                    }
            }

            // ---- row max (tree + 1 cross-half shuffle) ----
            float mx;
            {
                float t8[8];
#pragma unroll
                for (int i = 0; i < 8; ++i) {
                    float a = fmaxf(sacc[0][i], sacc[0][i + 8]);
                    float c = fmaxf(sacc[1][i], sacc[1][i + 8]);
                    t8[i] = fmaxf(a, c);
                }
                float t4a = fmaxf(t8[0], t8[1]), t4b = fmaxf(t8[2], t8[3]);
                float t4c = fmaxf(t8[4], t8[5]), t4d = fmaxf(t8[6], t8[7]);
                mx = fmaxf(fmaxf(t4a, t4b), fmaxf(t4c, t4d));
                mx = fmaxf(mx, __shfl_xor(mx, 32));
            }

            // ---- defer-max: rescale only when max grew past threshold ----
            if (!__all(mx <= m + THR_RAW)) {
                float nm = fmaxf(m, mx);
                float al = exp2f(CC * (m - nm));
                m = nm;
                lrow *= al;
#pragma unroll
                for (int r = 0; r < 16; ++r) {
                    float af = __shfl(al, (r & 3) + 8 * (r >> 2) + 4 * l5, 64);
                    o[0][r] *= af; o[1][r] *= af; o[2][r] *= af; o[3][r] *= af;
                }
            }
            float mcm = -CC * m;

            // ---- P = 2^(CC*s - CC*m), row sum ----
            f32x16 p[2];
#pragma unroll
            for (int kt2 = 0; kt2 < 2; ++kt2)
#pragma unroll
                for (int r = 0; r < 16; ++r)
                    p[kt2][r] = exp2f(__builtin_fmaf(CC, sacc[kt2][r], mcm));
            {
                float s8[8];
#pragma unroll
                for (int i = 0; i < 8; ++i)
                    s8[i] = (p[0][i] + p[0][i + 8]) + (p[1][i] + p[1][i + 8]);
                float s4a = s8[0] + s8[1], s4b = s8[2] + s8[3];
                float s4c = s8[4] + s8[5], s4d = s8[6] + s8[7];
                float rs = (s4a + s4b) + (s4c + s4d);
                rs += __shfl_xor(rs, 32);
                lrow += rs;
            }

            // ---- PV: build A-frags in-register (cvt_pk + permlane32_swap) ----
#pragma unroll
            for (int ks = 0; ks < 4; ++ks) {
                int e = ks & 1, kh = ks >> 1;
                u32 a0 = cvtpk(p[kh][8 * e + 0], p[kh][8 * e + 1]);
                u32 a1 = cvtpk(p[kh][8 * e + 2], p[kh][8 * e + 3]);
                u32 b0 = cvtpk(p[kh][8 * e + 4], p[kh][8 * e + 5]);
                u32 b1 = cvtpk(p[kh][8 * e + 6], p[kh][8 * e + 7]);
                u32x2 s0 = __builtin_amdgcn_permlane32_swap(a0, b0, false, false);
                u32x2 s1 = __builtin_amdgcn_permlane32_swap(a1, b1, false, false);
                union { u32 u[4]; bf16x8 v; } pu;
                pu.u[0] = s0[0]; pu.u[1] = s1[0]; pu.u[2] = s0[1]; pu.u[3] = s1[1];
                bf16x8 pf = pu.v;
#pragma unroll
                for (int dt = 0; dt < 4; ++dt) {
                    bf16x8 vf = *reinterpret_cast<const bf16x8*>(
                        Vbase + (dt * 32 + l32) * 64 + ((ks * 16 + koff) ^ xorm));
                    o[dt] = __builtin_amdgcn_mfma_f32_32x32x16_bf16(
                        pf, vf, o[dt], 0, 0, 0);
                }
            }
        }
    }

    // ---- epilogue: normalize (broadcast 1/l to reg-dim) and store ----
    float inv = 1.0f / lrow;
#pragma unroll
    for (int r = 0; r < 16; ++r) {
        int ql = (r & 3) + 8 * (r >> 2) + 4 * l5;
        float iv = __shfl(inv, ql, 64);
        int trow = qt * 128 + w * 32 + ql;
        size_t base = ((size_t)b * T_ + trow) * C_ + h * HS_ + l32;
#pragma unroll
        for (int dt = 0; dt < 4; ++dt)
            aout[base + dt * 32] = f2bf(o[dt][r] * iv);
    }
}

// ---------------- launch ----------------
extern "C" void kernel_launch(void* const* d_in, const int* in_sizes, int n_in,
                              void* d_out, int out_size, void* d_ws, size_t ws_size,
                              hipStream_t stream)
{
    const float* x      = (const float*)d_in[0];
    const float* w_qkv  = (const float*)d_in[1];
    const float* b_qkv  = (const float*)d_in[2];
    const float* w_proj = (const float*)d_in[3];
    const float* b_proj = (const float*)d_in[4];
    const float* fcos   = (const float*)d_in[5];
    const float* fsin   = (const float*)d_in[6];

    float* y  = (float*)d_out;
    float* kc = y + (size_t)B_ * T_ * C_;
    float* vc = kc + (size_t)B_ * NKVH_ * T_ * HS_;

    // R5-proven workspace layout (71.3 MB)
    char* ws = (char*)d_ws;
    u16* xb     = (u16*)(ws);
    u16* wprojT = (u16*)(ws);
    u16* wqkvT = (u16*)(ws + 16777216);
    u16* kbuf  = (u16*)(ws + 16777216);
    u16* vbuf  = (u16*)(ws + 16777216 + 4194304);
    u16* vtb   = (u16*)(ws + 16777216 + 8388608);
    u16* qkv  = (u16*)(ws + 29360128);
    u16* aout = (u16*)(ws + 29360128);
    u16* qbuf = (u16*)(ws + 54525952);

    cast_f32_bf16<<<M_ * C_ / 1024, 256, 0, stream>>>(x, xb, M_ * C_);
    transpose_cast_f32_bf16<<<dim3(NQKV / 32, C_ / 32), 256, 0, stream>>>(
        w_qkv, wqkvT, C_, NQKV);
    gemm8<8, 1><<<dim3(M_ / 256, NQKV / 256), 512, 0, stream>>>(
        xb, wqkvT, b_qkv, qkv, M_, NQKV, C_);
    rope_scatter<<<M_, 256, 0, stream>>>(qkv, fcos, fsin, qbuf, kbuf, vbuf, kc, vc);
    transpose_bf16_batched<<<dim3(HS_ / 32, T_ / 32, B_ * NKVH_), 256, 0, stream>>>(
        vbuf, vtb, T_, HS_);
    transpose_cast_f32_bf16<<<dim3(C_ / 32, C_ / 32), 256, 0, stream>>>(
        w_proj, wprojT, C_, C_);
    attn_kernel<<<dim3(T_ / 128, B_ * NH_), 256, 0, stream>>>(qbuf, kbuf, vtb, aout);
    gemm8<4, 0><<<dim3(M_ / 128, C_ / 256), 512, 0, stream>>>(
        aout, wprojT, b_proj, y, M_, C_, C_);
}